// Round 1
// baseline (74.667 us; speedup 1.0000x reference)
//
#include <hip/hip_runtime.h>
#include <stdint.h>

// Problem constants (fixed shapes from the reference)
#define HEADS 8
#define DIM   512
#define HD    64
#define NE    16      // entities per sentence
#define NS    64      // sentences
#define NB    64      // batch

typedef short bf16x8 __attribute__((ext_vector_type(8)));
typedef float f32x4  __attribute__((ext_vector_type(4)));

__device__ __forceinline__ unsigned short f2bf(float f) {
    union { float f; uint32_t u; } v; v.f = f;
    uint32_t u = v.u;
    u += 0x7fffu + ((u >> 16) & 1u);   // RNE
    return (unsigned short)(u >> 16);
}
__device__ __forceinline__ float bf2f(unsigned short b) {
    union { uint32_t u; float f; } v; v.u = ((uint32_t)b) << 16;
    return v.f;
}

// ---------------------------------------------------------------------------
// K0a: qvec[d] = sum_j query[j] * wq[d][j] + bq[d]         (512 outputs)
// grid 16 x 256: block = 32 outputs, 8-way K split, LDS reduce
// ---------------------------------------------------------------------------
__global__ __launch_bounds__(256) void k_qvec(
    const float* __restrict__ qp, const float* __restrict__ wq,
    const float* __restrict__ bq, float* __restrict__ qvec)
{
    __shared__ float red[32][9];
    const int t = threadIdx.x;
    const int dl = t >> 3, js = t & 7;
    const int d = blockIdx.x * 32 + dl;
    const float* w = wq + (size_t)d * DIM + js * 64;
    const float* q = qp + js * 64;
    float acc = 0.f;
    #pragma unroll 8
    for (int i = 0; i < 64; i++) acc += w[i] * q[i];
    red[dl][js] = acc;
    __syncthreads();
    if (t < 32) {
        float s = 0.f;
        #pragma unroll
        for (int j = 0; j < 8; j++) s += red[t][j];
        const int dd = blockIdx.x * 32 + t;
        qvec[dd] = s + bq[dd];
    }
}

// ---------------------------------------------------------------------------
// K0b: u_bf[h][d'] = bf16( sum_{j<64} qvec[h*64+j] * wk[h*64+j][d'] )
// rows h = 8..15 zeroed (score MFMA reads 16 rows; junk heads never used).
// The per-head constant q_h . bk_h is softmax-invariant -> bk unused.
// grid 16 x 256
// ---------------------------------------------------------------------------
__global__ __launch_bounds__(256) void k_uproj(
    const float* __restrict__ qvec, const float* __restrict__ wk,
    unsigned short* __restrict__ u_bf)
{
    const int h = blockIdx.x;
    const int t = threadIdx.x;
    if (h >= HEADS) {                 // zero pad rows (512 bf16 = 256 dwords)
        ((uint32_t*)u_bf)[h * 256 + t] = 0u;
        return;
    }
    __shared__ float qs[HD];
    if (t < HD) qs[t] = qvec[h * HD + t];
    __syncthreads();
    for (int c = t; c < DIM; c += 256) {
        const float* w = wk + (size_t)(h * HD) * DIM + c;
        float acc = 0.f;
        #pragma unroll 4
        for (int j = 0; j < HD; j++) acc += qs[j] * w[(size_t)j * DIM];
        u_bf[h * DIM + c] = f2bf(acc);
    }
}

// ---------------------------------------------------------------------------
// K1: fused score/softmax/weighted-aggregation. One block per (s,b).
//   scores[e][h] = scale * sum_d ent_bf[e][d] * u_bf[h][d]   (one wave, MFMA)
//   attn = softmax over e (shuffle-reduce; D-layout: e = 4g+j, h = lane&15)
//   weighted[sb][h*512+d] = sum_e attn[h][e] * ent[e][d]     (scalar, 256 thr)
// ent_bf LDS rows XOR-swizzled: byte ^= (e&7)<<4 (avoids 1024B-stride conflicts)
// ---------------------------------------------------------------------------
__global__ __launch_bounds__(256) void k_attn(
    const float* __restrict__ ents, const unsigned short* __restrict__ u_bf,
    unsigned short* __restrict__ weighted)
{
    __shared__ unsigned short ent_bf[NE * DIM];   // 16 KB, swizzled
    __shared__ float attn_s[NE][16];              // [e][h], h<8 valid
    const int t = threadIdx.x;
    const int bid = blockIdx.x;
    const int s = bid >> 6, b = bid & 63;

    // --- stage entities: 16 threads per entity row, float4 coalesced ---
    {
        const int e = t >> 4, c = t & 15;
        const float* src = ents + ((size_t)(s * NE + e) * NB + b) * DIM;
        const uint32_t swz  = (uint32_t)((e & 7) << 4);
        const uint32_t rowb = (uint32_t)e * (DIM * 2);
        #pragma unroll
        for (int i = 0; i < 8; i++) {
            const int d0 = 4 * c + 64 * i;
            const float4 v = *(const float4*)(src + d0);
            ushort4 hv;
            hv.x = f2bf(v.x); hv.y = f2bf(v.y); hv.z = f2bf(v.z); hv.w = f2bf(v.w);
            *(ushort4*)((char*)ent_bf + ((rowb + (uint32_t)d0 * 2u) ^ swz)) = hv;
        }
    }
    __syncthreads();

    // --- wave 0: score MFMA + softmax ---
    if (t < 64) {
        const int m = t & 15, g = t >> 4;
        const uint32_t aswz = (uint32_t)((m & 7) << 4);
        const uint32_t arow = (uint32_t)m * (DIM * 2);
        const unsigned short* urow = u_bf + m * DIM;   // B^T fragment from global (L2-hot)
        f32x4 acc = {0.f, 0.f, 0.f, 0.f};
        #pragma unroll
        for (int kk = 0; kk < DIM; kk += 32) {
            const int kp = kk + g * 8;
            bf16x8 af = *(const bf16x8*)((const char*)ent_bf + ((arow + (uint32_t)kp * 2u) ^ aswz));
            bf16x8 bf = *(const bf16x8*)(urow + kp);
            acc = __builtin_amdgcn_mfma_f32_16x16x32_bf16(af, bf, acc, 0, 0, 0);
        }
        // lane holds scores[e = 4g+j][h = m]; softmax over e
        const float scale = 0.125f;   // 1/sqrt(64)
        float s0 = acc[0]*scale, s1 = acc[1]*scale, s2 = acc[2]*scale, s3 = acc[3]*scale;
        float mx = fmaxf(fmaxf(s0, s1), fmaxf(s2, s3));
        mx = fmaxf(mx, __shfl_xor(mx, 16));
        mx = fmaxf(mx, __shfl_xor(mx, 32));
        const float p0 = __expf(s0 - mx), p1 = __expf(s1 - mx);
        const float p2 = __expf(s2 - mx), p3 = __expf(s3 - mx);
        float sm = p0 + p1 + p2 + p3;
        sm += __shfl_xor(sm, 16);
        sm += __shfl_xor(sm, 32);
        const float inv = 1.f / sm;
        attn_s[4 * g + 0][m] = p0 * inv;
        attn_s[4 * g + 1][m] = p1 * inv;
        attn_s[4 * g + 2][m] = p2 * inv;
        attn_s[4 * g + 3][m] = p3 * inv;
    }
    __syncthreads();

    // --- weighted sum: thread owns d0 = 2t, 2t+1 for all 8 heads ---
    float wa[HEADS], wb[HEADS];
    #pragma unroll
    for (int h = 0; h < HEADS; h++) { wa[h] = 0.f; wb[h] = 0.f; }
    const int d0 = 2 * t;
    #pragma unroll
    for (int ee = 0; ee < NE; ee++) {
        const uint32_t off = (((uint32_t)(ee * DIM + d0)) * 2u) ^ ((uint32_t)((ee & 7) << 4));
        const uint32_t pr = *(const uint32_t*)((const char*)ent_bf + off);
        const float v0 = bf2f((unsigned short)(pr & 0xffffu));
        const float v1 = bf2f((unsigned short)(pr >> 16));
        const float4 a0 = *(const float4*)&attn_s[ee][0];   // broadcast reads
        const float4 a1 = *(const float4*)&attn_s[ee][4];
        wa[0] += a0.x * v0; wb[0] += a0.x * v1;
        wa[1] += a0.y * v0; wb[1] += a0.y * v1;
        wa[2] += a0.z * v0; wb[2] += a0.z * v1;
        wa[3] += a0.w * v0; wb[3] += a0.w * v1;
        wa[4] += a1.x * v0; wb[4] += a1.x * v1;
        wa[5] += a1.y * v0; wb[5] += a1.y * v1;
        wa[6] += a1.z * v0; wb[6] += a1.z * v1;
        wa[7] += a1.w * v0; wb[7] += a1.w * v1;
    }
    unsigned short* wrow = weighted + (size_t)bid * (HEADS * DIM);
    #pragma unroll
    for (int h = 0; h < HEADS; h++) {
        const uint32_t pk = (uint32_t)f2bf(wa[h]) | ((uint32_t)f2bf(wb[h]) << 16);
        *(uint32_t*)(wrow + h * DIM + d0) = pk;
    }
}

// ---------------------------------------------------------------------------
// K2/K3: C[M=4096, 64 cols per y] = A(bf16) @ B^T(fp32->bf16) + bias
// BM=64, BN=64, BK=64; 4 waves, each wave a 16-row strip x 64 cols.
//   K2: A=weighted (lda 4096, col off 512*y=head), B=wv rows 64y.. -> ctx bf16
//   K3: A=ctx      (lda 512),                      B=wo rows 64y.. -> out f32
// ---------------------------------------------------------------------------
template <typename CT>
__global__ __launch_bounds__(256) void k_gemm(
    const unsigned short* __restrict__ A, int lda, int aOffY,
    const float* __restrict__ B, int ldb, int bOffY,
    const float* __restrict__ bias, CT* __restrict__ C, int ldc, int cOffY, int K)
{
    __shared__ unsigned short a_s[64][72];
    __shared__ unsigned short b_s[64][72];
    const int t = threadIdx.x;
    const int m0 = blockIdx.x * 64;
    const int y  = blockIdx.y;
    const int w = t >> 6, l = t & 63;
    const int m = l & 15, g = l >> 4;
    const int lr = t >> 2, lk = (t & 3) * 16;

    const unsigned short* Ap = A + (size_t)(m0 + lr) * lda + (size_t)aOffY * y;
    const float* Bp = B + (size_t)(bOffY * y + lr) * ldb;

    f32x4 acc[4];
    #pragma unroll
    for (int i = 0; i < 4; i++) acc[i] = (f32x4){0.f, 0.f, 0.f, 0.f};

    for (int k0 = 0; k0 < K; k0 += 64) {
        const ushort4 av0 = *(const ushort4*)(Ap + k0 + lk);
        const ushort4 av1 = *(const ushort4*)(Ap + k0 + lk + 4);
        const ushort4 av2 = *(const ushort4*)(Ap + k0 + lk + 8);
        const ushort4 av3 = *(const ushort4*)(Ap + k0 + lk + 12);
        const float4 bv0 = *(const float4*)(Bp + k0 + lk);
        const float4 bv1 = *(const float4*)(Bp + k0 + lk + 4);
        const float4 bv2 = *(const float4*)(Bp + k0 + lk + 8);
        const float4 bv3 = *(const float4*)(Bp + k0 + lk + 12);
        *(ushort4*)&a_s[lr][lk]      = av0;
        *(ushort4*)&a_s[lr][lk + 4]  = av1;
        *(ushort4*)&a_s[lr][lk + 8]  = av2;
        *(ushort4*)&a_s[lr][lk + 12] = av3;
        ushort4 h0, h1, h2, h3;
        h0.x = f2bf(bv0.x); h0.y = f2bf(bv0.y); h0.z = f2bf(bv0.z); h0.w = f2bf(bv0.w);
        h1.x = f2bf(bv1.x); h1.y = f2bf(bv1.y); h1.z = f2bf(bv1.z); h1.w = f2bf(bv1.w);
        h2.x = f2bf(bv2.x); h2.y = f2bf(bv2.y); h2.z = f2bf(bv2.z); h2.w = f2bf(bv2.w);
        h3.x = f2bf(bv3.x); h3.y = f2bf(bv3.y); h3.z = f2bf(bv3.z); h3.w = f2bf(bv3.w);
        *(ushort4*)&b_s[lr][lk]      = h0;
        *(ushort4*)&b_s[lr][lk + 4]  = h1;
        *(ushort4*)&b_s[lr][lk + 8]  = h2;
        *(ushort4*)&b_s[lr][lk + 12] = h3;
        __syncthreads();
        #pragma unroll
        for (int kk = 0; kk < 64; kk += 32) {
            const int kp = kk + g * 8;
            const bf16x8 af = *(const bf16x8*)&a_s[w * 16 + m][kp];
            const bf16x8 b0 = *(const bf16x8*)&b_s[ 0 + m][kp];
            const bf16x8 b1 = *(const bf16x8*)&b_s[16 + m][kp];
            const bf16x8 b2 = *(const bf16x8*)&b_s[32 + m][kp];
            const bf16x8 b3 = *(const bf16x8*)&b_s[48 + m][kp];
            acc[0] = __builtin_amdgcn_mfma_f32_16x16x32_bf16(af, b0, acc[0], 0, 0, 0);
            acc[1] = __builtin_amdgcn_mfma_f32_16x16x32_bf16(af, b1, acc[1], 0, 0, 0);
            acc[2] = __builtin_amdgcn_mfma_f32_16x16x32_bf16(af, b2, acc[2], 0, 0, 0);
            acc[3] = __builtin_amdgcn_mfma_f32_16x16x32_bf16(af, b3, acc[3], 0, 0, 0);
        }
        __syncthreads();
    }

    const int colbase = cOffY * y;
    #pragma unroll
    for (int nt = 0; nt < 4; nt++) {
        const int col = colbase + nt * 16 + m;
        const float bs = bias[col];
        #pragma unroll
        for (int j = 0; j < 4; j++) {
            const int row = m0 + w * 16 + g * 4 + j;
            const float val = acc[nt][j] + bs;
            if (sizeof(CT) == 2) {
                ((unsigned short*)C)[(size_t)row * ldc + col] = f2bf(val);
            } else {
                ((float*)C)[(size_t)row * ldc + col] = val;
            }
        }
    }
}

// ---------------------------------------------------------------------------
extern "C" void kernel_launch(void* const* d_in, const int* in_sizes, int n_in,
                              void* d_out, int out_size, void* d_ws, size_t ws_size,
                              hipStream_t stream)
{
    const float* ents = (const float*)d_in[0];
    const float* qp   = (const float*)d_in[1];
    const float* wq   = (const float*)d_in[2];
    const float* wk   = (const float*)d_in[3];
    const float* wv   = (const float*)d_in[4];
    const float* wo   = (const float*)d_in[5];
    const float* bq   = (const float*)d_in[6];
    // d_in[7] = bk: per-head softmax-invariant constant -> algebraically unused
    const float* bv   = (const float*)d_in[8];
    const float* bo   = (const float*)d_in[9];

    // workspace layout (needs ~37.8 MB)
    char* ws = (char*)d_ws;
    float*          qvec     = (float*)ws;                               // 2 KB
    unsigned short* u_bf     = (unsigned short*)(ws + 2048);             // 16 KB [16][512]
    unsigned short* weighted = (unsigned short*)(ws + 32768);            // 32 MB [4096][4096]
    unsigned short* ctx      = (unsigned short*)(ws + 32768 + 33554432); // 4 MB [4096][512]

    k_qvec <<<16, 256, 0, stream>>>(qp, wq, bq, qvec);
    k_uproj<<<16, 256, 0, stream>>>(qvec, wk, u_bf);
    k_attn <<<4096, 256, 0, stream>>>(ents, u_bf, weighted);
    k_gemm<unsigned short><<<dim3(64, 8), 256, 0, stream>>>(
        weighted, HEADS * DIM, DIM, wv, DIM, HD, bv, ctx, DIM, HD, DIM);
    k_gemm<float><<<dim3(64, 8), 256, 0, stream>>>(
        ctx, DIM, 0, wo, DIM, HD, bo, (float*)d_out, DIM, HD, DIM);
}

// Round 2
// 68.296 us; speedup vs baseline: 1.0933x; 1.0933x over previous
//
#include <hip/hip_runtime.h>
#include <stdint.h>

// Problem constants (fixed shapes from the reference)
#define HEADS 8
#define DIM   512
#define HD    64
#define NE    16      // entities per sentence
#define NS    64      // sentences
#define NB    64      // batch

typedef short bf16x8 __attribute__((ext_vector_type(8)));
typedef float f32x4  __attribute__((ext_vector_type(4)));

__device__ __forceinline__ unsigned short f2bf(float f) {
    union { float f; uint32_t u; } v; v.f = f;
    uint32_t u = v.u;
    u += 0x7fffu + ((u >> 16) & 1u);   // RNE
    return (unsigned short)(u >> 16);
}
__device__ __forceinline__ float bf2f(unsigned short b) {
    union { uint32_t u; float f; } v; v.u = ((uint32_t)b) << 16;
    return v.f;
}

// ---------------------------------------------------------------------------
// K0: fused prep.
//   blocks [0,64):    qvec[d] = q . wq[d] + bq[d]   (8 outputs/block, 32-lane K-split)
//   blocks [64,320):  wv -> bf16
//   blocks [320,576): wo -> bf16
// ---------------------------------------------------------------------------
__global__ __launch_bounds__(256) void k_prep(
    const float* __restrict__ qp, const float* __restrict__ wq,
    const float* __restrict__ bq, const float* __restrict__ wv,
    const float* __restrict__ wo, float* __restrict__ qvec,
    unsigned short* __restrict__ wv_bf, unsigned short* __restrict__ wo_bf)
{
    const int bid = blockIdx.x;
    const int t = threadIdx.x;
    if (bid < 64) {
        const int dl = t >> 5, js = t & 31;
        const int d = bid * 8 + dl;
        const float* w = wq + (size_t)d * DIM + js * 16;
        const float* q = qp + js * 16;
        float acc = 0.f;
        #pragma unroll
        for (int i = 0; i < 16; i++) acc += w[i] * q[i];
        #pragma unroll
        for (int msk = 16; msk >= 1; msk >>= 1) acc += __shfl_xor(acc, msk);
        if (js == 0) qvec[d] = acc + bq[d];
        return;
    }
    const bool is_v = bid < 320;
    const float* src = is_v ? wv : wo;
    unsigned short* dst = is_v ? wv_bf : wo_bf;
    const int li = ((is_v ? bid - 64 : bid - 320) * 1024 + t * 4);
    const float4 v = *(const float4*)(src + li);
    ushort4 hv;
    hv.x = f2bf(v.x); hv.y = f2bf(v.y); hv.z = f2bf(v.z); hv.w = f2bf(v.w);
    *(ushort4*)(dst + li) = hv;
}

// ---------------------------------------------------------------------------
// K1: u_bf[h][c] = bf16( sum_{j<64} qvec[h*64+j] * wk[h*64+j][c] )
//   blocks [0,64): h = bid>>3, 64-col group cg = bid&7. 64 threads (1 wave).
//   blocks [64,72): zero pad rows h = 8..15.
// q_h . bk_h is softmax-invariant -> bk unused.
// ---------------------------------------------------------------------------
__global__ __launch_bounds__(64) void k_uproj(
    const float* __restrict__ qvec, const float* __restrict__ wk,
    unsigned short* __restrict__ u_bf)
{
    const int bid = blockIdx.x;
    const int l = threadIdx.x;
    if (bid >= 64) {                       // zero rows 8..15 (512 bf16 each)
        const int row = 8 + (bid - 64);
        ((uint4*)(u_bf + row * DIM))[l & 63] = (uint4){0u, 0u, 0u, 0u};
        return;
    }
    const int h = bid >> 3, cg = bid & 7;
    __shared__ float qs[HD];
    qs[l] = qvec[h * HD + l];
    __syncthreads();
    const int c = cg * 64 + l;
    const float* w = wk + (size_t)(h * HD) * DIM + c;
    float acc = 0.f;
    #pragma unroll 8
    for (int j = 0; j < HD; j++) acc += qs[j] * w[(size_t)j * DIM];
    u_bf[h * DIM + c] = f2bf(acc);
}

// ---------------------------------------------------------------------------
// K2: fused score/softmax/weighted-aggregation.
// Block = (sentence s, 4 consecutive batch slots). 1024 blocks, 4 waves.
//   stage:    ent[(s*16+e)*64 + bg+bb][d] -> LDS bf16 (XOR-swizzled on e)
//   score:    wave w computes scores[e][h] for bb=w via one MFMA chain
//   softmax:  shuffle over e (D-layout: e = 4g+j, h = lane&15)
//   weighted: wave w, lane l owns d0=8l: acc[h][8] over 16 entities
// ---------------------------------------------------------------------------
__global__ __launch_bounds__(256, 2) void k_attn(
    const float* __restrict__ ents, const unsigned short* __restrict__ u_bf,
    unsigned short* __restrict__ weighted)
{
    __shared__ unsigned short ent[NE * 4 * DIM];   // 64 KB, swizzled
    __shared__ float attn_s[4][NE][16];            // [bb][e][h], h<8 valid
    const int t = threadIdx.x;
    const int bid = blockIdx.x;
    const int s = bid >> 4;
    const int bg = (bid & 15) << 2;

    // --- stage: 8192 float4 chunks; wave-contiguous 1KB segments ---
    {
        const float* base = ents + ((size_t)(s * NE) * NB + bg) * DIM;
        #pragma unroll 4
        for (int i = 0; i < 32; i++) {
            const int li = t + 256 * i;            // 0..8191
            const int e  = li >> 9;
            const int bb = (li >> 7) & 3;
            const int d0 = (li & 127) << 2;
            const float4 v = *(const float4*)(base + ((size_t)e * NB + bb) * DIM + d0);
            ushort4 hv;
            hv.x = f2bf(v.x); hv.y = f2bf(v.y); hv.z = f2bf(v.z); hv.w = f2bf(v.w);
            const uint32_t off = (uint32_t)((((e * 4 + bb) << 9) + d0) << 1) ^ (uint32_t)((e & 7) << 4);
            *(ushort4*)((char*)ent + off) = hv;
        }
    }
    __syncthreads();

    const int w = t >> 6, l = t & 63;
    const int m = l & 15, g = l >> 4;

    // --- score MFMA + softmax (wave w handles bb = w) ---
    {
        const uint32_t aswz = (uint32_t)((m & 7) << 4);
        const uint32_t abase = (uint32_t)((m * 4 + w) << 10);   // *512*2 bytes
        const unsigned short* urow = u_bf + m * DIM;
        f32x4 acc = {0.f, 0.f, 0.f, 0.f};
        #pragma unroll
        for (int kk = 0; kk < DIM; kk += 32) {
            const int kp = kk + g * 8;
            bf16x8 af = *(const bf16x8*)((const char*)ent + ((abase + (uint32_t)(kp << 1)) ^ aswz));
            bf16x8 bf = *(const bf16x8*)(urow + kp);
            acc = __builtin_amdgcn_mfma_f32_16x16x32_bf16(af, bf, acc, 0, 0, 0);
        }
        const float scale = 0.125f;   // 1/sqrt(64)
        float s0 = acc[0]*scale, s1 = acc[1]*scale, s2 = acc[2]*scale, s3 = acc[3]*scale;
        float mx = fmaxf(fmaxf(s0, s1), fmaxf(s2, s3));
        mx = fmaxf(mx, __shfl_xor(mx, 16));
        mx = fmaxf(mx, __shfl_xor(mx, 32));
        const float p0 = __expf(s0 - mx), p1 = __expf(s1 - mx);
        const float p2 = __expf(s2 - mx), p3 = __expf(s3 - mx);
        float sm = p0 + p1 + p2 + p3;
        sm += __shfl_xor(sm, 16);
        sm += __shfl_xor(sm, 32);
        const float inv = 1.f / sm;
        attn_s[w][4 * g + 0][m] = p0 * inv;
        attn_s[w][4 * g + 1][m] = p1 * inv;
        attn_s[w][4 * g + 2][m] = p2 * inv;
        attn_s[w][4 * g + 3][m] = p3 * inv;
    }
    __syncthreads();

    // --- weighted sum: wave w, lane owns d0 = 8l (8 d x 8 heads in regs) ---
    float acc2[HEADS][8];
    #pragma unroll
    for (int h = 0; h < HEADS; h++)
        #pragma unroll
        for (int j = 0; j < 8; j++) acc2[h][j] = 0.f;

    const int d0 = l << 3;
    #pragma unroll
    for (int e = 0; e < NE; e++) {
        const uint32_t off = (uint32_t)((((e * 4 + w) << 9) + d0) << 1) ^ (uint32_t)((e & 7) << 4);
        const bf16x8 ev = *(const bf16x8*)((const char*)ent + off);
        const unsigned short* ep = (const unsigned short*)&ev;
        float evf[8];
        #pragma unroll
        for (int j = 0; j < 8; j++) evf[j] = bf2f(ep[j]);
        const float4 a0 = *(const float4*)&attn_s[w][e][0];
        const float4 a1 = *(const float4*)&attn_s[w][e][4];
        float av[8] = {a0.x, a0.y, a0.z, a0.w, a1.x, a1.y, a1.z, a1.w};
        #pragma unroll
        for (int h = 0; h < HEADS; h++)
            #pragma unroll
            for (int j = 0; j < 8; j++) acc2[h][j] += av[h] * evf[j];
    }
    unsigned short* wrow = weighted + ((size_t)(s * NB + bg + w) << 12);
    #pragma unroll
    for (int h = 0; h < HEADS; h++) {
        bf16x8 ov;
        #pragma unroll
        for (int j = 0; j < 8; j++) ov[j] = (short)f2bf(acc2[h][j]);
        *(bf16x8*)(wrow + h * DIM + d0) = ov;
    }
}

// ---------------------------------------------------------------------------
// K3/K4: C[M=4096, 64 cols per y] = A(bf16) @ B^T(bf16) + bias
// BM=64, BN=64, BK=64; 4 waves, each wave a 16-row strip x 64 cols.
//   K3: A=weighted (lda 4096, col off 512*y=head), B=wv_bf rows 64y.. -> ctx bf16
//   K4: A=ctx      (lda 512),                      B=wo_bf rows 64y.. -> out f32
// ---------------------------------------------------------------------------
template <typename CT>
__global__ __launch_bounds__(256) void k_gemm(
    const unsigned short* __restrict__ A, int lda, int aOffY,
    const unsigned short* __restrict__ B, int ldb, int bOffY,
    const float* __restrict__ bias, CT* __restrict__ C, int ldc, int cOffY, int K)
{
    __shared__ unsigned short a_s[64][72];
    __shared__ unsigned short b_s[64][72];
    const int t = threadIdx.x;
    const int m0 = blockIdx.x * 64;
    const int y  = blockIdx.y;
    const int w = t >> 6, l = t & 63;
    const int m = l & 15, g = l >> 4;
    const int lr = t >> 2, lk = (t & 3) * 16;

    const unsigned short* Ap = A + (size_t)(m0 + lr) * lda + (size_t)aOffY * y;
    const unsigned short* Bp = B + (size_t)(bOffY * y + lr) * ldb;

    f32x4 acc[4];
    #pragma unroll
    for (int i = 0; i < 4; i++) acc[i] = (f32x4){0.f, 0.f, 0.f, 0.f};

    for (int k0 = 0; k0 < K; k0 += 64) {
        const ushort4 av0 = *(const ushort4*)(Ap + k0 + lk);
        const ushort4 av1 = *(const ushort4*)(Ap + k0 + lk + 4);
        const ushort4 av2 = *(const ushort4*)(Ap + k0 + lk + 8);
        const ushort4 av3 = *(const ushort4*)(Ap + k0 + lk + 12);
        const ushort4 bv0 = *(const ushort4*)(Bp + k0 + lk);
        const ushort4 bv1 = *(const ushort4*)(Bp + k0 + lk + 4);
        const ushort4 bv2 = *(const ushort4*)(Bp + k0 + lk + 8);
        const ushort4 bv3 = *(const ushort4*)(Bp + k0 + lk + 12);
        *(ushort4*)&a_s[lr][lk]      = av0;
        *(ushort4*)&a_s[lr][lk + 4]  = av1;
        *(ushort4*)&a_s[lr][lk + 8]  = av2;
        *(ushort4*)&a_s[lr][lk + 12] = av3;
        *(ushort4*)&b_s[lr][lk]      = bv0;
        *(ushort4*)&b_s[lr][lk + 4]  = bv1;
        *(ushort4*)&b_s[lr][lk + 8]  = bv2;
        *(ushort4*)&b_s[lr][lk + 12] = bv3;
        __syncthreads();
        #pragma unroll
        for (int kk = 0; kk < 64; kk += 32) {
            const int kp = kk + g * 8;
            const bf16x8 af = *(const bf16x8*)&a_s[w * 16 + m][kp];
            const bf16x8 b0 = *(const bf16x8*)&b_s[ 0 + m][kp];
            const bf16x8 b1 = *(const bf16x8*)&b_s[16 + m][kp];
            const bf16x8 b2 = *(const bf16x8*)&b_s[32 + m][kp];
            const bf16x8 b3 = *(const bf16x8*)&b_s[48 + m][kp];
            acc[0] = __builtin_amdgcn_mfma_f32_16x16x32_bf16(af, b0, acc[0], 0, 0, 0);
            acc[1] = __builtin_amdgcn_mfma_f32_16x16x32_bf16(af, b1, acc[1], 0, 0, 0);
            acc[2] = __builtin_amdgcn_mfma_f32_16x16x32_bf16(af, b2, acc[2], 0, 0, 0);
            acc[3] = __builtin_amdgcn_mfma_f32_16x16x32_bf16(af, b3, acc[3], 0, 0, 0);
        }
        __syncthreads();
    }

    const int colbase = cOffY * y;
    #pragma unroll
    for (int nt = 0; nt < 4; nt++) {
        const int col = colbase + nt * 16 + m;
        const float bs = bias[col];
        #pragma unroll
        for (int j = 0; j < 4; j++) {
            const int row = m0 + w * 16 + g * 4 + j;
            const float val = acc[nt][j] + bs;
            if (sizeof(CT) == 2) {
                ((unsigned short*)C)[(size_t)row * ldc + col] = f2bf(val);
            } else {
                ((float*)C)[(size_t)row * ldc + col] = val;
            }
        }
    }
}

// ---------------------------------------------------------------------------
extern "C" void kernel_launch(void* const* d_in, const int* in_sizes, int n_in,
                              void* d_out, int out_size, void* d_ws, size_t ws_size,
                              hipStream_t stream)
{
    const float* ents = (const float*)d_in[0];
    const float* qp   = (const float*)d_in[1];
    const float* wq   = (const float*)d_in[2];
    const float* wk   = (const float*)d_in[3];
    const float* wv   = (const float*)d_in[4];
    const float* wo   = (const float*)d_in[5];
    const float* bq   = (const float*)d_in[6];
    // d_in[7] = bk: per-head softmax-invariant constant -> algebraically unused
    const float* bv   = (const float*)d_in[8];
    const float* bo   = (const float*)d_in[9];

    // workspace layout (~40 MB)
    char* ws = (char*)d_ws;
    float*          qvec     = (float*)ws;                                 // 2 KB
    unsigned short* u_bf     = (unsigned short*)(ws + 4096);               // 16 KB [16][512]
    unsigned short* wv_bf    = (unsigned short*)(ws + 65536);              // 512 KB
    unsigned short* wo_bf    = (unsigned short*)(ws + 65536 + 524288);     // 512 KB
    unsigned short* weighted = (unsigned short*)(ws + 2097152);            // 32 MB [4096][4096]
    unsigned short* ctx      = (unsigned short*)(ws + 2097152 + 33554432); // 4 MB [4096][512]

    k_prep <<<576, 256, 0, stream>>>(qp, wq, bq, wv, wo, qvec, wv_bf, wo_bf);
    k_uproj<<<72, 64, 0, stream>>>(qvec, wk, u_bf);
    k_attn <<<1024, 256, 0, stream>>>(ents, u_bf, weighted);
    k_gemm<unsigned short><<<dim3(64, 8), 256, 0, stream>>>(
        weighted, HEADS * DIM, DIM, wv_bf, DIM, HD, bv, ctx, DIM, HD, DIM);
    k_gemm<float><<<dim3(64, 8), 256, 0, stream>>>(
        ctx, DIM, 0, wo_bf, DIM, HD, bo, (float*)d_out, DIM, HD, DIM);
}